// Round 3
// baseline (48.294 us; speedup 1.0000x reference)
//
#include <hip/hip_runtime.h>

// out[j] = sum_i alpha[i] * T[lab_obs[i], lab_x[j]] * matern52(xobs[i], x[j]; ls)
// Two-kernel plan: pack_rows pre-splits xobs rows into bf16 hi/lo (scaled by
// -2/ls^2) + na + alpha + domain label, 48 B/row in d_ws. matern_main computes
// sq_ij = na_i + nb_j + A.B via mfma_f32_16x16x32_bf16 (split-bf16 K-packing),
// then the Matern-5/2 tail on the VALU, accumulating alpha*W directly.

typedef __attribute__((ext_vector_type(8))) short short8v;
typedef __attribute__((ext_vector_type(4))) float f32x4;
typedef __attribute__((ext_vector_type(4))) unsigned int u32x4;

#define BLOCK 256
#define DPT 8
#define SROWS 128          // rows per stage round
#define NROUNDS 2          // rounds per block -> 256 rows/block
#define COLS_PER_BLOCK 128 // 2 column-groups of 16 per wave
#define RSTRIDE 12         // floats per packed row (48 B, 16B-aligned quads)

__device__ __forceinline__ void split_pair(float a0, float a1,
                                           unsigned& hi, unsigned& lo) {
    unsigned u0 = __builtin_bit_cast(unsigned, a0);
    unsigned u1 = __builtin_bit_cast(unsigned, a1);
    unsigned h0 = u0 & 0xffff0000u, h1 = u1 & 0xffff0000u;
    float r0 = a0 - __builtin_bit_cast(float, h0);
    float r1 = a1 - __builtin_bit_cast(float, h1);
    unsigned l0 = __builtin_bit_cast(unsigned, r0);
    unsigned l1 = __builtin_bit_cast(unsigned, r1);
    hi = (h0 >> 16) | h1;
    lo = (l0 >> 16) | (l1 & 0xffff0000u);
}

__global__ __launch_bounds__(256) void pack_rows(
    const float* __restrict__ xobs, const float* __restrict__ alpha,
    const float* __restrict__ ls, const int* __restrict__ dro,
    float* __restrict__ pk, int N, int NP, int ND)
{
    const int i = blockIdx.x * 256 + threadIdx.x;
    if (i >= NP) return;
    float* rb = pk + (size_t)i * RSTRIDE;
    if (i < N) {
        const float rls  = 1.0f / ls[0];
        const float rls2 = rls * rls;
        const float m2   = -2.0f * rls2;
        float4 p0 = *(const float4*)(xobs + (size_t)i * DPT);
        float4 p1 = *(const float4*)(xobs + (size_t)i * DPT + 4);
        float vv[8] = {p0.x, p0.y, p0.z, p0.w, p1.x, p1.y, p1.z, p1.w};
        float na = 0.0f;
        unsigned hi[4], lo[4];
        #pragma unroll
        for (int k = 0; k < 4; ++k) {
            float a0 = vv[2*k], a1 = vv[2*k+1];
            na += a0*a0 + a1*a1;
            split_pair(a0*m2, a1*m2, hi[k], lo[k]);
        }
        na *= rls2;
        int labi = ND;
        for (int d = 0; d < ND; ++d)
            if (i >= dro[2*d] && i < dro[2*d+1]) labi = d;
        *(uint4*)(rb)     = make_uint4(hi[0], hi[1], hi[2], hi[3]);
        *(uint4*)(rb + 4) = make_uint4(lo[0], lo[1], lo[2], lo[3]);
        rb[8]  = na;
        rb[9]  = alpha[i];
        rb[10] = (float)labi;
        rb[11] = 0.0f;
    } else {
        *(uint4*)(rb)     = make_uint4(0u, 0u, 0u, 0u);
        *(uint4*)(rb + 4) = make_uint4(0u, 0u, 0u, 0u);
        rb[8] = 0.0f; rb[9] = 0.0f; rb[10] = (float)ND; rb[11] = 0.0f;
    }
}

__global__ __launch_bounds__(256) void matern_main(
    const float* __restrict__ x, const float* __restrict__ pk,
    const float* __restrict__ tfl, const float* __restrict__ ls,
    const int* __restrict__ drx,
    float* __restrict__ out, int M, int ND)
{
    __shared__ __align__(16) float buf[2][SROWS][RSTRIDE];
    __shared__ float wlab[16];

    const int tid  = threadIdx.x;
    const int wave = tid >> 6;
    const int lane = tid & 63;
    const int g    = lane >> 4;
    const int r15  = lane & 15;

    const int colBase = blockIdx.x * COLS_PER_BLOCK;
    const int rowBase = blockIdx.y * (SROWS * NROUNDS);

    // block-uniform column-domain label (128-col tile within one domain)
    int labj = ND;
    for (int d = 0; d < ND; ++d)
        if (colBase >= drx[2*d] && colBase < drx[2*d+1]) labj = d;

    // per-domain row weight for this column tile
    if (tid <= ND) {
        int d = tid; float w = 1.0f;
        if (d != labj && d < ND && labj < ND) {
            int a_ = min(d, labj), b_ = max(d, labj);
            int n  = a_ * (2*ND - a_ - 1) / 2 + (b_ - a_ - 1);
            w = 1.0f / (1.0f + __expf(-tfl[n]));
        }
        wlab[d] = w;
    }

    // ---- column fragments (2 groups of 16 columns per wave) ----
    const float rls  = 1.0f / ls[0];
    const float rls2 = rls * rls;
    const int j0 = colBase + wave * 32 + r15;
    const int j1 = j0 + 16;
    float nb[2]; short8v bfrag[2];
    #pragma unroll
    for (int c = 0; c < 2; ++c) {
        const int j = (c == 0) ? j0 : j1;
        float vv[8];
        if (j < M) {
            float4 p0 = *(const float4*)(x + (size_t)j * DPT);
            float4 p1 = *(const float4*)(x + (size_t)j * DPT + 4);
            vv[0]=p0.x; vv[1]=p0.y; vv[2]=p0.z; vv[3]=p0.w;
            vv[4]=p1.x; vv[5]=p1.y; vv[6]=p1.z; vv[7]=p1.w;
        } else {
            #pragma unroll
            for (int k = 0; k < 8; ++k) vv[k] = 0.0f;
        }
        float s2 = 0.0f;
        unsigned bh[4], bl[4];
        #pragma unroll
        for (int k = 0; k < 4; ++k) {
            s2 += vv[2*k]*vv[2*k] + vv[2*k+1]*vv[2*k+1];
            split_pair(vv[2*k], vv[2*k+1], bh[k], bl[k]);
        }
        nb[c] = s2 * rls2;
        u32x4 bw;
        #pragma unroll
        for (int k = 0; k < 4; ++k)
            bw[k] = (g == 3) ? 0u : ((g == 2) ? bl[k] : bh[k]);
        bfrag[c] = __builtin_bit_cast(short8v, bw);
    }

    // ---- staging machinery (all 256 threads; double-buffered) ----
    const int srow  = tid >> 1;
    const int spart = tid & 1;
    uint4 qA, qB;
    auto issue = [&](int rnd) {
        const float* src = pk + (size_t)(rowBase + rnd*SROWS + srow) * RSTRIDE + spart*4;
        qA = *(const uint4*)src;
        if (tid < SROWS) {
            const float* s2 = pk + (size_t)(rowBase + rnd*SROWS + tid) * RSTRIDE + 8;
            qB = *(const uint4*)s2;
        }
    };
    auto commit = [&](int b) {
        *(uint4*)(&buf[b][srow][spart*4]) = qA;
        if (tid < SROWS) {
            float na_  = __builtin_bit_cast(float, qB.x);
            float alp  = __builtin_bit_cast(float, qB.y);
            int   labi = (int)__builtin_bit_cast(float, qB.z);
            buf[b][tid][8] = na_;
            buf[b][tid][9] = alp * wlab[labi];
        }
    };

    const float SQRT5 = 2.23606797749979f;
    const float C53   = 1.6666666666666667f;   // 5/3
    const float EXPC  = -3.2259645291206594f;  // -sqrt5 * log2(e)

    float colacc0 = 0.0f, colacc1 = 0.0f;

    auto compute = [&](int b) {
        #pragma unroll
        for (int it = 0; it < SROWS/16; ++it) {
            const float* rblk = &buf[b][it*16][0];
            short8v afrag = *(const short8v*)(rblk + r15*RSTRIDE + ((g == 1) ? 4 : 0));
            f32x4 c0, c1; float awr[4];
            #pragma unroll
            for (int q = 0; q < 4; ++q) {
                float2 nw = *(const float2*)(rblk + (g*4 + q)*RSTRIDE + 8);
                c0[q]  = nw.x + nb[0];
                c1[q]  = nw.x + nb[1];
                awr[q] = nw.y;
            }
            f32x4 d0 = __builtin_amdgcn_mfma_f32_16x16x32_bf16(afrag, bfrag[0], c0, 0, 0, 0);
            f32x4 d1 = __builtin_amdgcn_mfma_f32_16x16x32_bf16(afrag, bfrag[1], c1, 0, 0, 0);
            #pragma unroll
            for (int q = 0; q < 4; ++q) {
                float sq0 = fmaxf(d0[q], 1e-12f);
                float dd0 = __builtin_amdgcn_sqrtf(sq0);
                float e0  = __builtin_amdgcn_exp2f(EXPC * dd0);
                float p0  = fmaf(C53, sq0, 1.0f) + SQRT5 * dd0;
                colacc0   = fmaf(p0 * e0, awr[q], colacc0);
                float sq1 = fmaxf(d1[q], 1e-12f);
                float dd1 = __builtin_amdgcn_sqrtf(sq1);
                float e1  = __builtin_amdgcn_exp2f(EXPC * dd1);
                float p1  = fmaf(C53, sq1, 1.0f) + SQRT5 * dd1;
                colacc1   = fmaf(p1 * e1, awr[q], colacc1);
            }
        }
    };

    issue(0);
    __syncthreads();          // wlab visible to all
    commit(0);
    __syncthreads();          // buf0 ready
    #pragma unroll
    for (int rnd = 0; rnd < NROUNDS; ++rnd) {
        if (rnd + 1 < NROUNDS) issue(rnd + 1);    // loads in flight over compute
        compute(rnd & 1);
        if (rnd + 1 < NROUNDS) {
            commit((rnd + 1) & 1);
            __syncthreads();
        }
    }

    // reduce the 4 k/D-row groups and accumulate
    colacc0 += __shfl_xor(colacc0, 16);
    colacc0 += __shfl_xor(colacc0, 32);
    colacc1 += __shfl_xor(colacc1, 16);
    colacc1 += __shfl_xor(colacc1, 32);
    if (g == 0) {
        if (j0 < M) atomicAdd(&out[j0], colacc0);
        if (j1 < M) atomicAdd(&out[j1], colacc1);
    }
}

extern "C" void kernel_launch(void* const* d_in, const int* in_sizes, int n_in,
                              void* d_out, int out_size, void* d_ws, size_t ws_size,
                              hipStream_t stream) {
    const float* x     = (const float*)d_in[0];
    const float* xobs  = (const float*)d_in[1];
    const float* alpha = (const float*)d_in[2];
    const float* tfl   = (const float*)d_in[3];
    const float* ls    = (const float*)d_in[4];
    const int*   dro   = (const int*)d_in[5];
    const int*   drx   = (const int*)d_in[6];
    float* out = (float*)d_out;

    const int M  = in_sizes[0] / DPT;
    const int N  = in_sizes[1] / DPT;
    const int ND = in_sizes[5] / 2;
    const int NP = (N + 255) & ~255;   // pad to a multiple of rows/block

    hipMemsetAsync(d_out, 0, (size_t)M * sizeof(float), stream);

    float* pk = (float*)d_ws;          // NP * 48 bytes
    pack_rows<<<dim3(NP / 256), dim3(256), 0, stream>>>(
        xobs, alpha, ls, dro, pk, N, NP, ND);

    dim3 grid((M + COLS_PER_BLOCK - 1) / COLS_PER_BLOCK, NP / (SROWS * NROUNDS));
    matern_main<<<grid, dim3(BLOCK), 0, stream>>>(
        x, pk, tfl, ls, drx, out, M, ND);
}